// Round 7
// baseline (232.005 us; speedup 1.0000x reference)
//
#include <hip/hip_runtime.h>

// Chamfer distance, B=16, N=M=4096, D=3.
// dist(i,j) = n1 + n2 - 2*x1.x2 as ONE bf16 MFMA per 32x32 tile (norms folded
// into padded K slots, hi/lo bf16 split => exact-grade; absmax 0.0 since R1).
// R11: DIAGNOSTIC round. chamfer_main has never appeared in top-5 (fills at
// ~40.6 us mask everything below). Two probe dispatches re-run the identical
// tile-stream 4x internally (~4x main dur -> guaranteed top-2, full counters),
// after reduce_rows, idempotent (same atomicMin values; rowm dead by then):
//   probe4 = body x4, launch_bounds(256,4)  (production cap 128)
//   probe2 = body x4, launch_bounds(256,2)  (cap 256 -> spill-vs-occupancy A/B)
// Decision matrix: probe4 WRITE>>50MB & probe2 WRITE~1MB -> spill: ship lb2.
// Both WRITE small + VALUBusy>60% -> VALU-issue-bound. Both pipes low ->
// latency-bound: deepen prefetch / LDS-stage. Production path = R10 exactly.

typedef __attribute__((ext_vector_type(8))) __bf16 bf16x8;
typedef __attribute__((ext_vector_type(16))) float f32x16;

#define PTS 4096
#define TILES 128  // PTS/32
#define NB 16

__device__ __forceinline__ unsigned f2bf(float f) {
  unsigned u = __float_as_uint(f);
  return (u + 0x7FFFu + ((u >> 16) & 1u)) >> 16;  // RNE bf16 bits
}
__device__ __forceinline__ float bf2f(unsigned s) {
  return __uint_as_float(s << 16);
}
__device__ __forceinline__ unsigned pk(unsigned lo, unsigned hi) {
  return (lo & 0xFFFFu) | (hi << 16);
}

// ---- prepack B-side fragments + init rowm + zero out ----
// Bfr[(((d*NB+b)*TILES+t)*2+h)*32 + l31]
// B k-vec: w0=[Hx Hy Hz Lx Ly Lz Hx Hy]  w1=[Hz nh nl 1 1 0 0 0], H,L split -2q.
__global__ __launch_bounds__(256) void prepack_b(const float* __restrict__ x1,
                                                 const float* __restrict__ x2,
                                                 uint4* __restrict__ Bfr,
                                                 unsigned* __restrict__ rowm,
                                                 float* __restrict__ out) {
  const int id = blockIdx.x * 256 + threadIdx.x;  // 2*NB*PTS = 131072
  rowm[id] = 0x7F800000u;                         // +inf (all dists >= 0)
  if (id < NB) out[id] = 0.f;                     // reduce uses atomicAdd
  const int d = id >> 16;
  const int b = (id >> 12) & (NB - 1);
  const int j = id & (PTS - 1);
  const float* q = (d ? x1 : x2) + (size_t)(b * PTS + j) * 3;
  const float x = q[0], y = q[1], z = q[2];
  const float sx = -2.f * x, sy = -2.f * y, sz = -2.f * z;
  const unsigned Hx = f2bf(sx), Hy = f2bf(sy), Hz = f2bf(sz);
  const unsigned Lx = f2bf(sx - bf2f(Hx));
  const unsigned Ly = f2bf(sy - bf2f(Hy));
  const unsigned Lz = f2bf(sz - bf2f(Hz));
  const float n = fmaf(x, x, fmaf(y, y, z * z));
  const unsigned nh = f2bf(n), nl = f2bf(n - bf2f(nh));
  const unsigned one = 0x3F80u;
  uint4 w0, w1;
  w0.x = pk(Hx, Hy); w0.y = pk(Hz, Lx); w0.z = pk(Ly, Lz); w0.w = pk(Hx, Hy);
  w1.x = pk(Hz, nh); w1.y = pk(nl, one); w1.z = pk(one, 0u); w1.w = 0u;
  uint4* base =
      Bfr + ((size_t)((d * NB + b) * TILES + (j >> 5)) * 2) * 32 + (j & 31);
  base[0]  = w0;   // half 0
  base[32] = w1;   // half 1
}

// ---- shared body: 256 threads (4 waves). All 4 waves stream the SAME 64
// col-tiles (different rows) -> L1 temporal reuse. No LDS, no barriers.
// REPEAT>1 re-runs the stream (idempotent) for probe self-timing.
template <int REPEAT>
__device__ __forceinline__ void chamfer_body(const float* __restrict__ x1,
                                             const float* __restrict__ x2,
                                             const uint4* __restrict__ Bfr,
                                             unsigned* __restrict__ rowm) {
  const int s  = blockIdx.x;           // 64 slices: (dir, batch, colhalf)
  const int d  = s & 1;
  const int b  = (s >> 1) & (NB - 1);
  const int ch = (s >> 5) & 1;
  const int rg = blockIdx.y;           // 16 row-groups of 256 rows

  const int tid  = threadIdx.x;
  const int lane = tid & 63;
  const int half = lane >> 5;          // K-half this lane supplies to MFMA
  const int l31  = lane & 31;
  const int wave = tid >> 6;

  // --- build A fragments from raw points (row tiles t0, t0+1) ---
  // A k-vec: w0=[hx hy hz hx hy hz lx ly]  w1=[lz 1 1 nh nl 0 0 0]
  const float* P = d ? x2 : x1;
  const int t0 = rg * 8 + wave * 2;
  bf16x8 af[2];
#pragma unroll
  for (int rr = 0; rr < 2; ++rr) {
    const int r = (t0 + rr) * 32 + l31;
    const float* p = P + (size_t)(b * PTS + r) * 3;
    const float x = p[0], y = p[1], zc = p[2];
    const unsigned hx = f2bf(x), hy = f2bf(y), hz = f2bf(zc);
    const unsigned lx = f2bf(x - bf2f(hx));
    const unsigned ly = f2bf(y - bf2f(hy));
    const unsigned lz = f2bf(zc - bf2f(hz));
    const float n = fmaf(x, x, fmaf(y, y, zc * zc));
    const unsigned nh = f2bf(n), nl = f2bf(n - bf2f(nh));
    const unsigned one = 0x3F80u;
    uint4 w0, w1;
    w0.x = pk(hx, hy); w0.y = pk(hz, hx); w0.z = pk(hy, hz); w0.w = pk(lx, ly);
    w1.x = pk(lz, one); w1.y = pk(one, nh); w1.z = pk(nl, 0u); w1.w = 0u;
    uint4 w;
    w.x = half ? w1.x : w0.x; w.y = half ? w1.y : w0.y;
    w.z = half ? w1.z : w0.z; w.w = half ? w1.w : w0.w;
    af[rr] = *(const bf16x8*)&w;
  }
  const bf16x8 af0 = af[0], af1 = af[1];

  f32x16 zero;
#pragma unroll
  for (int e = 0; e < 16; ++e) zero[e] = 0.f;

  float rm0[16], rm1[16];
#pragma unroll
  for (int e = 0; e < 16; ++e) { rm0[e] = 3.0e38f; rm1[e] = 3.0e38f; }

  // --- stream this col-half's 64 tiles; 4-slot ring, 2 loads in flight ---
  const uint4* bp = Bfr + ((size_t)((d * NB + b) * TILES + ch * 64) * 2) * 32;
  const int off = half * 32 + l31;  // within a tile: h*32 + col
  for (int rep = 0; rep < REPEAT; ++rep) {
    bf16x8 buf[4];
#pragma unroll
    for (int t = 0; t < 2; ++t) buf[t] = *(const bf16x8*)&bp[t * 64 + off];

#pragma unroll 2
    for (int g = 0; g < 32; ++g) {
      const int cur = (g & 1) * 2;
      const int nxt = ((g + 1) & 1) * 2;
      const int pf  = ((g + 1) & 31) * 2;  // wrap: redundant last pf, safe
      buf[nxt]     = *(const bf16x8*)&bp[pf * 64 + off];
      buf[nxt + 1] = *(const bf16x8*)&bp[(pf + 1) * 64 + off];
      const bf16x8 b0 = buf[cur], b1 = buf[cur + 1];
      const f32x16 a00 =
          __builtin_amdgcn_mfma_f32_32x32x16_bf16(af0, b0, zero, 0, 0, 0);
      const f32x16 a01 =
          __builtin_amdgcn_mfma_f32_32x32x16_bf16(af0, b1, zero, 0, 0, 0);
#pragma unroll
      for (int e = 0; e < 16; ++e)
        rm0[e] = fminf(fminf(a00[e], a01[e]), rm0[e]);  // v_min3_f32
      const f32x16 a10 =
          __builtin_amdgcn_mfma_f32_32x32x16_bf16(af1, b0, zero, 0, 0, 0);
      const f32x16 a11 =
          __builtin_amdgcn_mfma_f32_32x32x16_bf16(af1, b1, zero, 0, 0, 0);
#pragma unroll
      for (int e = 0; e < 16; ++e)
        rm1[e] = fminf(fminf(a10[e], a11[e]), rm1[e]);
    }
  }

  // --- per-row min over this wave's 32 cols-per-half, then uint atomicMin ---
  // C/D layout: col = lane&31, row_local = (e&3) + 8*(e>>2) + 4*half.
  unsigned* rbase = rowm + (size_t)(d * NB + b) * PTS + t0 * 32;
#pragma unroll
  for (int e = 0; e < 16; ++e) {
    float v = rm0[e];
    v = fminf(v, __shfl_xor(v, 1));
    v = fminf(v, __shfl_xor(v, 2));
    v = fminf(v, __shfl_xor(v, 4));
    v = fminf(v, __shfl_xor(v, 8));
    v = fminf(v, __shfl_xor(v, 16));
    if (l31 == e) {
      const int rl = (e & 3) + 8 * (e >> 2) + 4 * half;
      atomicMin(rbase + rl, __float_as_uint(fmaxf(v, 0.f)));
    }
  }
#pragma unroll
  for (int e = 0; e < 16; ++e) {
    float v = rm1[e];
    v = fminf(v, __shfl_xor(v, 1));
    v = fminf(v, __shfl_xor(v, 2));
    v = fminf(v, __shfl_xor(v, 4));
    v = fminf(v, __shfl_xor(v, 8));
    v = fminf(v, __shfl_xor(v, 16));
    if (l31 == e) {
      const int rl = 32 + (e & 3) + 8 * (e >> 2) + 4 * half;
      atomicMin(rbase + rl, __float_as_uint(fmaxf(v, 0.f)));
    }
  }
}

__global__ __launch_bounds__(256, 4) void chamfer_main(
    const float* __restrict__ x1, const float* __restrict__ x2,
    const uint4* __restrict__ Bfr, unsigned* __restrict__ rowm) {
  chamfer_body<1>(x1, x2, Bfr, rowm);
}

// Probes: 4x internal repeat -> ~4x main dur -> lands in top-5 with counters.
__global__ __launch_bounds__(256, 4) void chamfer_probe4(
    const float* __restrict__ x1, const float* __restrict__ x2,
    const uint4* __restrict__ Bfr, unsigned* __restrict__ rowm) {
  chamfer_body<4>(x1, x2, Bfr, rowm);
}
__global__ __launch_bounds__(256, 2) void chamfer_probe2(
    const float* __restrict__ x1, const float* __restrict__ x2,
    const uint4* __restrict__ Bfr, unsigned* __restrict__ rowm) {
  chamfer_body<4>(x1, x2, Bfr, rowm);
}

// ---- reduce: out[b] += partial sums of rowmin; 64 blocks (b, quarter) ----
__global__ __launch_bounds__(256) void reduce_rows(
    const unsigned* __restrict__ rowm, float* __restrict__ out) {
  const int b = blockIdx.x >> 2;
  const int seg = blockIdx.x & 3;
  const int tid = threadIdx.x;
  const unsigned* r0 = rowm + (size_t)b * PTS + seg * 1024;
  const unsigned* r1 = rowm + (size_t)(NB + b) * PTS + seg * 1024;
  float s = 0.f;
  for (int i = tid; i < 1024; i += 256)
    s += __uint_as_float(r0[i]) + __uint_as_float(r1[i]);
  s += __shfl_xor(s, 1);
  s += __shfl_xor(s, 2);
  s += __shfl_xor(s, 4);
  s += __shfl_xor(s, 8);
  s += __shfl_xor(s, 16);
  s += __shfl_xor(s, 32);
  __shared__ float acc[4];
  if ((tid & 63) == 0) acc[tid >> 6] = s;
  __syncthreads();
  if (tid == 0)
    atomicAdd(&out[b], (acc[0] + acc[1] + acc[2] + acc[3]) * (1.f / PTS));
}

extern "C" void kernel_launch(void* const* d_in, const int* in_sizes, int n_in,
                              void* d_out, int out_size, void* d_ws,
                              size_t ws_size, hipStream_t stream) {
  const float* x1 = (const float*)d_in[0];
  const float* x2 = (const float*)d_in[1];
  float* out = (float*)d_out;

  uint4* Bfr = (uint4*)d_ws;  // 2*NB*TILES*2*32 uint4 = 4 MB
  unsigned* rowm =
      (unsigned*)((char*)d_ws + (size_t)2 * NB * TILES * 2 * 32 * 16);

  prepack_b<<<(2 * NB * PTS) / 256, 256, 0, stream>>>(x1, x2, Bfr, rowm, out);
  dim3 grid(64, NB);  // x = (dir,b,ch) slice -> XCD = x%8 ; y = row-group
  chamfer_main<<<grid, 256, 0, stream>>>(x1, x2, Bfr, rowm);
  reduce_rows<<<64, 256, 0, stream>>>(rowm, out);
  // Diagnostic probes (idempotent; rowm is dead after reduce_rows).
  chamfer_probe4<<<grid, 256, 0, stream>>>(x1, x2, Bfr, rowm);
  chamfer_probe2<<<grid, 256, 0, stream>>>(x1, x2, Bfr, rowm);
}

// Round 8
// 105.804 us; speedup vs baseline: 2.1928x; 2.1928x over previous
//
#include <hip/hip_runtime.h>

// Chamfer distance, B=16, N=M=4096, D=3.
// dist(i,j) = n1 + n2 - 2*x1.x2 as ONE bf16 MFMA per 32x32 tile (norms folded
// into padded K slots, hi/lo bf16 split => exact-grade; absmax 0.0 since R1).
// R12: occupancy fix. R11 probes PROVED the main stream: VGPR=52, zero spill,
// cap-128 == cap-256 (probe4==probe2), MfmaUtil 38 / VALUBusy 50 / Occ 32%.
// Issue-bound with idle SIMD slots; limiter is the GRID (1024 blocks = 4
// blocks/CU = 16 waves/CU, while VGPR=52 allows 8 blocks/CU = 32 waves).
// Split col stream into quarters: grid.x 64->128 (dir,b,cq), 32 tiles/block,
// 2048 blocks = 8 blocks/CU. Same total MFMA/fold work; 2x prologue/epilogue
// (small). Body/codegen otherwise identical to the proven R10 shape.

typedef __attribute__((ext_vector_type(8))) __bf16 bf16x8;
typedef __attribute__((ext_vector_type(16))) float f32x16;

#define PTS 4096
#define TILES 128  // PTS/32
#define NB 16

__device__ __forceinline__ unsigned f2bf(float f) {
  unsigned u = __float_as_uint(f);
  return (u + 0x7FFFu + ((u >> 16) & 1u)) >> 16;  // RNE bf16 bits
}
__device__ __forceinline__ float bf2f(unsigned s) {
  return __uint_as_float(s << 16);
}
__device__ __forceinline__ unsigned pk(unsigned lo, unsigned hi) {
  return (lo & 0xFFFFu) | (hi << 16);
}

// ---- prepack B-side fragments + init rowm + zero out ----
// Bfr[(((d*NB+b)*TILES+t)*2+h)*32 + l31]
// B k-vec: w0=[Hx Hy Hz Lx Ly Lz Hx Hy]  w1=[Hz nh nl 1 1 0 0 0], H,L split -2q.
__global__ __launch_bounds__(256) void prepack_b(const float* __restrict__ x1,
                                                 const float* __restrict__ x2,
                                                 uint4* __restrict__ Bfr,
                                                 unsigned* __restrict__ rowm,
                                                 float* __restrict__ out) {
  const int id = blockIdx.x * 256 + threadIdx.x;  // 2*NB*PTS = 131072
  rowm[id] = 0x7F800000u;                         // +inf (all dists >= 0)
  if (id < NB) out[id] = 0.f;                     // reduce uses atomicAdd
  const int d = id >> 16;
  const int b = (id >> 12) & (NB - 1);
  const int j = id & (PTS - 1);
  const float* q = (d ? x1 : x2) + (size_t)(b * PTS + j) * 3;
  const float x = q[0], y = q[1], z = q[2];
  const float sx = -2.f * x, sy = -2.f * y, sz = -2.f * z;
  const unsigned Hx = f2bf(sx), Hy = f2bf(sy), Hz = f2bf(sz);
  const unsigned Lx = f2bf(sx - bf2f(Hx));
  const unsigned Ly = f2bf(sy - bf2f(Hy));
  const unsigned Lz = f2bf(sz - bf2f(Hz));
  const float n = fmaf(x, x, fmaf(y, y, z * z));
  const unsigned nh = f2bf(n), nl = f2bf(n - bf2f(nh));
  const unsigned one = 0x3F80u;
  uint4 w0, w1;
  w0.x = pk(Hx, Hy); w0.y = pk(Hz, Lx); w0.z = pk(Ly, Lz); w0.w = pk(Hx, Hy);
  w1.x = pk(Hz, nh); w1.y = pk(nl, one); w1.z = pk(one, 0u); w1.w = 0u;
  uint4* base =
      Bfr + ((size_t)((d * NB + b) * TILES + (j >> 5)) * 2) * 32 + (j & 31);
  base[0]  = w0;   // half 0
  base[32] = w1;   // half 1
}

// ---- main: 256 threads (4 waves). All 4 waves stream the SAME 32 col-tiles
// (different rows) -> L1 temporal reuse. No LDS, no barriers.
__global__ __launch_bounds__(256, 4) void chamfer_main(
    const float* __restrict__ x1, const float* __restrict__ x2,
    const uint4* __restrict__ Bfr, unsigned* __restrict__ rowm) {
  const int s  = blockIdx.x;           // 128 slices: (dir, batch, col-quarter)
  const int d  = s & 1;
  const int b  = (s >> 1) & (NB - 1);
  const int cq = (s >> 5) & 3;
  const int rg = blockIdx.y;           // 16 row-groups of 256 rows

  const int tid  = threadIdx.x;
  const int lane = tid & 63;
  const int half = lane >> 5;          // K-half this lane supplies to MFMA
  const int l31  = lane & 31;
  const int wave = tid >> 6;

  // --- build A fragments from raw points (row tiles t0, t0+1) ---
  // A k-vec: w0=[hx hy hz hx hy hz lx ly]  w1=[lz 1 1 nh nl 0 0 0]
  const float* P = d ? x2 : x1;
  const int t0 = rg * 8 + wave * 2;
  bf16x8 af[2];
#pragma unroll
  for (int rr = 0; rr < 2; ++rr) {
    const int r = (t0 + rr) * 32 + l31;
    const float* p = P + (size_t)(b * PTS + r) * 3;
    const float x = p[0], y = p[1], zc = p[2];
    const unsigned hx = f2bf(x), hy = f2bf(y), hz = f2bf(zc);
    const unsigned lx = f2bf(x - bf2f(hx));
    const unsigned ly = f2bf(y - bf2f(hy));
    const unsigned lz = f2bf(zc - bf2f(hz));
    const float n = fmaf(x, x, fmaf(y, y, zc * zc));
    const unsigned nh = f2bf(n), nl = f2bf(n - bf2f(nh));
    const unsigned one = 0x3F80u;
    uint4 w0, w1;
    w0.x = pk(hx, hy); w0.y = pk(hz, hx); w0.z = pk(hy, hz); w0.w = pk(lx, ly);
    w1.x = pk(lz, one); w1.y = pk(one, nh); w1.z = pk(nl, 0u); w1.w = 0u;
    uint4 w;
    w.x = half ? w1.x : w0.x; w.y = half ? w1.y : w0.y;
    w.z = half ? w1.z : w0.z; w.w = half ? w1.w : w0.w;
    af[rr] = *(const bf16x8*)&w;
  }
  const bf16x8 af0 = af[0], af1 = af[1];

  f32x16 zero;
#pragma unroll
  for (int e = 0; e < 16; ++e) zero[e] = 0.f;

  float rm0[16], rm1[16];
#pragma unroll
  for (int e = 0; e < 16; ++e) { rm0[e] = 3.0e38f; rm1[e] = 3.0e38f; }

  // --- stream this col-quarter's 32 tiles; 4-slot ring, 2 loads in flight ---
  const uint4* bp = Bfr + ((size_t)((d * NB + b) * TILES + cq * 32) * 2) * 32;
  const int off = half * 32 + l31;  // within a tile: h*32 + col
  bf16x8 buf[4];
#pragma unroll
  for (int t = 0; t < 2; ++t) buf[t] = *(const bf16x8*)&bp[t * 64 + off];

#pragma unroll 2
  for (int g = 0; g < 16; ++g) {
    const int cur = (g & 1) * 2;
    const int nxt = ((g + 1) & 1) * 2;
    const int pf  = ((g + 1) & 15) * 2;  // wrap: last prefetch redundant, safe
    buf[nxt]     = *(const bf16x8*)&bp[pf * 64 + off];
    buf[nxt + 1] = *(const bf16x8*)&bp[(pf + 1) * 64 + off];
    const bf16x8 b0 = buf[cur], b1 = buf[cur + 1];
    const f32x16 a00 =
        __builtin_amdgcn_mfma_f32_32x32x16_bf16(af0, b0, zero, 0, 0, 0);
    const f32x16 a01 =
        __builtin_amdgcn_mfma_f32_32x32x16_bf16(af0, b1, zero, 0, 0, 0);
#pragma unroll
    for (int e = 0; e < 16; ++e)
      rm0[e] = fminf(fminf(a00[e], a01[e]), rm0[e]);  // v_min3_f32
    const f32x16 a10 =
        __builtin_amdgcn_mfma_f32_32x32x16_bf16(af1, b0, zero, 0, 0, 0);
    const f32x16 a11 =
        __builtin_amdgcn_mfma_f32_32x32x16_bf16(af1, b1, zero, 0, 0, 0);
#pragma unroll
    for (int e = 0; e < 16; ++e)
      rm1[e] = fminf(fminf(a10[e], a11[e]), rm1[e]);
  }

  // --- per-row min over this wave's 32 cols-per-half, then uint atomicMin ---
  // C/D layout: col = lane&31, row_local = (e&3) + 8*(e>>2) + 4*half.
  unsigned* rbase = rowm + (size_t)(d * NB + b) * PTS + t0 * 32;
#pragma unroll
  for (int e = 0; e < 16; ++e) {
    float v = rm0[e];
    v = fminf(v, __shfl_xor(v, 1));
    v = fminf(v, __shfl_xor(v, 2));
    v = fminf(v, __shfl_xor(v, 4));
    v = fminf(v, __shfl_xor(v, 8));
    v = fminf(v, __shfl_xor(v, 16));
    if (l31 == e) {
      const int rl = (e & 3) + 8 * (e >> 2) + 4 * half;
      atomicMin(rbase + rl, __float_as_uint(fmaxf(v, 0.f)));
    }
  }
#pragma unroll
  for (int e = 0; e < 16; ++e) {
    float v = rm1[e];
    v = fminf(v, __shfl_xor(v, 1));
    v = fminf(v, __shfl_xor(v, 2));
    v = fminf(v, __shfl_xor(v, 4));
    v = fminf(v, __shfl_xor(v, 8));
    v = fminf(v, __shfl_xor(v, 16));
    if (l31 == e) {
      const int rl = 32 + (e & 3) + 8 * (e >> 2) + 4 * half;
      atomicMin(rbase + rl, __float_as_uint(fmaxf(v, 0.f)));
    }
  }
}

// ---- reduce: out[b] += partial sums of rowmin; 64 blocks (b, quarter) ----
__global__ __launch_bounds__(256) void reduce_rows(
    const unsigned* __restrict__ rowm, float* __restrict__ out) {
  const int b = blockIdx.x >> 2;
  const int seg = blockIdx.x & 3;
  const int tid = threadIdx.x;
  const unsigned* r0 = rowm + (size_t)b * PTS + seg * 1024;
  const unsigned* r1 = rowm + (size_t)(NB + b) * PTS + seg * 1024;
  float s = 0.f;
  for (int i = tid; i < 1024; i += 256)
    s += __uint_as_float(r0[i]) + __uint_as_float(r1[i]);
  s += __shfl_xor(s, 1);
  s += __shfl_xor(s, 2);
  s += __shfl_xor(s, 4);
  s += __shfl_xor(s, 8);
  s += __shfl_xor(s, 16);
  s += __shfl_xor(s, 32);
  __shared__ float acc[4];
  if ((tid & 63) == 0) acc[tid >> 6] = s;
  __syncthreads();
  if (tid == 0)
    atomicAdd(&out[b], (acc[0] + acc[1] + acc[2] + acc[3]) * (1.f / PTS));
}

extern "C" void kernel_launch(void* const* d_in, const int* in_sizes, int n_in,
                              void* d_out, int out_size, void* d_ws,
                              size_t ws_size, hipStream_t stream) {
  const float* x1 = (const float*)d_in[0];
  const float* x2 = (const float*)d_in[1];
  float* out = (float*)d_out;

  uint4* Bfr = (uint4*)d_ws;  // 2*NB*TILES*2*32 uint4 = 4 MB
  unsigned* rowm =
      (unsigned*)((char*)d_ws + (size_t)2 * NB * TILES * 2 * 32 * 16);

  prepack_b<<<(2 * NB * PTS) / 256, 256, 0, stream>>>(x1, x2, Bfr, rowm, out);
  dim3 grid(128, NB);  // x = (dir,b,cq) slice -> XCD = x%8 ; y = row-group
  chamfer_main<<<grid, 256, 0, stream>>>(x1, x2, Bfr, rowm);
  reduce_rows<<<64, 256, 0, stream>>>(rowm, out);
}

// Round 9
// 94.653 us; speedup vs baseline: 2.4511x; 1.1178x over previous
//
#include <hip/hip_runtime.h>

// Chamfer distance, B=16, N=M=4096, D=3.
// dist(i,j) = n1 + n2 - 2*x1.x2 as ONE bf16 MFMA per 32x32 tile (norms folded
// into padded K slots, hi/lo bf16 split => exact-grade; absmax 0.0 since R1).
// R13: LDS-stage the column panel. R12's counters showed the hot loop is
// COLD-LATENCY-bound (MfmaUtil 12.8 / VALUBusy 30 / Occ 30, FETCH tiny, no
// spill): prepack scatters Bfr across all 8 XCDs' L2s, so the streaming loads
// pay LLC latency (~400-500cyc) that a 2-4 tile VGPR ring can't cover, and
// occupancy is register-capped at ~4 waves/SIMD so TLP can't hide it either.
// Fix: each block copies its 32-tile (32 KB) column panel to LDS once
// (coalesced, one __syncthreads), hot loop reads ds_read_b128 (~60-120cyc,
// covered by the distance-2 ring). 4 waves' loads dedup'd; zero extra VGPRs.
// LDS 32 KB -> still 4 blocks/CU (register-capped anyway).

typedef __attribute__((ext_vector_type(8))) __bf16 bf16x8;
typedef __attribute__((ext_vector_type(16))) float f32x16;

#define PTS 4096
#define TILES 128  // PTS/32
#define NB 16

__device__ __forceinline__ unsigned f2bf(float f) {
  unsigned u = __float_as_uint(f);
  return (u + 0x7FFFu + ((u >> 16) & 1u)) >> 16;  // RNE bf16 bits
}
__device__ __forceinline__ float bf2f(unsigned s) {
  return __uint_as_float(s << 16);
}
__device__ __forceinline__ unsigned pk(unsigned lo, unsigned hi) {
  return (lo & 0xFFFFu) | (hi << 16);
}

// ---- prepack B-side fragments + init rowm + zero out ----
// Bfr[(((d*NB+b)*TILES+t)*2+h)*32 + l31]
// B k-vec: w0=[Hx Hy Hz Lx Ly Lz Hx Hy]  w1=[Hz nh nl 1 1 0 0 0], H,L split -2q.
__global__ __launch_bounds__(256) void prepack_b(const float* __restrict__ x1,
                                                 const float* __restrict__ x2,
                                                 uint4* __restrict__ Bfr,
                                                 unsigned* __restrict__ rowm,
                                                 float* __restrict__ out) {
  const int id = blockIdx.x * 256 + threadIdx.x;  // 2*NB*PTS = 131072
  rowm[id] = 0x7F800000u;                         // +inf (all dists >= 0)
  if (id < NB) out[id] = 0.f;                     // reduce uses atomicAdd
  const int d = id >> 16;
  const int b = (id >> 12) & (NB - 1);
  const int j = id & (PTS - 1);
  const float* q = (d ? x1 : x2) + (size_t)(b * PTS + j) * 3;
  const float x = q[0], y = q[1], z = q[2];
  const float sx = -2.f * x, sy = -2.f * y, sz = -2.f * z;
  const unsigned Hx = f2bf(sx), Hy = f2bf(sy), Hz = f2bf(sz);
  const unsigned Lx = f2bf(sx - bf2f(Hx));
  const unsigned Ly = f2bf(sy - bf2f(Hy));
  const unsigned Lz = f2bf(sz - bf2f(Hz));
  const float n = fmaf(x, x, fmaf(y, y, z * z));
  const unsigned nh = f2bf(n), nl = f2bf(n - bf2f(nh));
  const unsigned one = 0x3F80u;
  uint4 w0, w1;
  w0.x = pk(Hx, Hy); w0.y = pk(Hz, Lx); w0.z = pk(Ly, Lz); w0.w = pk(Hx, Hy);
  w1.x = pk(Hz, nh); w1.y = pk(nl, one); w1.z = pk(one, 0u); w1.w = 0u;
  uint4* base =
      Bfr + ((size_t)((d * NB + b) * TILES + (j >> 5)) * 2) * 32 + (j & 31);
  base[0]  = w0;   // half 0
  base[32] = w1;   // half 1
}

// ---- main: 256 threads (4 waves). Block stages its 32-tile col panel into
// LDS once, then all 4 waves stream it from LDS (different rows).
// grid.x = 128 slices (dir,b,cq) -> XCD = x%8 ; grid.y = 16 row-groups.
__global__ __launch_bounds__(256, 4) void chamfer_main(
    const float* __restrict__ x1, const float* __restrict__ x2,
    const uint4* __restrict__ Bfr, unsigned* __restrict__ rowm) {
  const int s  = blockIdx.x;           // 128 slices: (dir, batch, col-quarter)
  const int d  = s & 1;
  const int b  = (s >> 1) & (NB - 1);
  const int cq = (s >> 5) & 3;
  const int rg = blockIdx.y;           // 16 row-groups of 256 rows

  const int tid  = threadIdx.x;
  const int lane = tid & 63;
  const int half = lane >> 5;          // K-half this lane supplies to MFMA
  const int l31  = lane & 31;
  const int wave = tid >> 6;

  __shared__ uint4 lds[2048];          // 32 tiles x 1 KB = 32 KB

  // --- stage the col panel: 8 coalesced uint4 per thread ---
  const uint4* bp = Bfr + ((size_t)((d * NB + b) * TILES + cq * 32) * 2) * 32;
#pragma unroll
  for (int k = 0; k < 8; ++k) lds[tid + k * 256] = bp[tid + k * 256];

  // --- build A fragments from raw points (row tiles t0, t0+1) ---
  // A k-vec: w0=[hx hy hz hx hy hz lx ly]  w1=[lz 1 1 nh nl 0 0 0]
  const float* P = d ? x2 : x1;
  const int t0 = rg * 8 + wave * 2;
  bf16x8 af[2];
#pragma unroll
  for (int rr = 0; rr < 2; ++rr) {
    const int r = (t0 + rr) * 32 + l31;
    const float* p = P + (size_t)(b * PTS + r) * 3;
    const float x = p[0], y = p[1], zc = p[2];
    const unsigned hx = f2bf(x), hy = f2bf(y), hz = f2bf(zc);
    const unsigned lx = f2bf(x - bf2f(hx));
    const unsigned ly = f2bf(y - bf2f(hy));
    const unsigned lz = f2bf(zc - bf2f(hz));
    const float n = fmaf(x, x, fmaf(y, y, zc * zc));
    const unsigned nh = f2bf(n), nl = f2bf(n - bf2f(nh));
    const unsigned one = 0x3F80u;
    uint4 w0, w1;
    w0.x = pk(hx, hy); w0.y = pk(hz, hx); w0.z = pk(hy, hz); w0.w = pk(lx, ly);
    w1.x = pk(lz, one); w1.y = pk(one, nh); w1.z = pk(nl, 0u); w1.w = 0u;
    uint4 w;
    w.x = half ? w1.x : w0.x; w.y = half ? w1.y : w0.y;
    w.z = half ? w1.z : w0.z; w.w = half ? w1.w : w0.w;
    af[rr] = *(const bf16x8*)&w;
  }
  const bf16x8 af0 = af[0], af1 = af[1];

  f32x16 zero;
#pragma unroll
  for (int e = 0; e < 16; ++e) zero[e] = 0.f;

  float rm0[16], rm1[16];
#pragma unroll
  for (int e = 0; e < 16; ++e) { rm0[e] = 3.0e38f; rm1[e] = 3.0e38f; }

  __syncthreads();  // panel staged (read-only afterwards: no more barriers)

  // --- stream 32 tiles from LDS; 4-slot ring, 2 reads in flight ---
  const uint4* tp = &lds[half * 32 + l31];  // tile stride = 64 uint4
  bf16x8 buf[4];
  buf[0] = *(const bf16x8*)&tp[0];
  buf[1] = *(const bf16x8*)&tp[64];

#pragma unroll 2
  for (int g = 0; g < 16; ++g) {
    const int cur = (g & 1) * 2;
    const int nxt = ((g + 1) & 1) * 2;
    const int pf  = ((g + 1) & 15) * 2;  // wrap: last prefetch redundant, safe
    buf[nxt]     = *(const bf16x8*)&tp[pf * 64];
    buf[nxt + 1] = *(const bf16x8*)&tp[(pf + 1) * 64];
    const bf16x8 b0 = buf[cur], b1 = buf[cur + 1];
    const f32x16 a00 =
        __builtin_amdgcn_mfma_f32_32x32x16_bf16(af0, b0, zero, 0, 0, 0);
    const f32x16 a01 =
        __builtin_amdgcn_mfma_f32_32x32x16_bf16(af0, b1, zero, 0, 0, 0);
#pragma unroll
    for (int e = 0; e < 16; ++e)
      rm0[e] = fminf(fminf(a00[e], a01[e]), rm0[e]);  // v_min3_f32
    const f32x16 a10 =
        __builtin_amdgcn_mfma_f32_32x32x16_bf16(af1, b0, zero, 0, 0, 0);
    const f32x16 a11 =
        __builtin_amdgcn_mfma_f32_32x32x16_bf16(af1, b1, zero, 0, 0, 0);
#pragma unroll
    for (int e = 0; e < 16; ++e)
      rm1[e] = fminf(fminf(a10[e], a11[e]), rm1[e]);
  }

  // --- per-row min over this wave's 32 cols-per-half, then uint atomicMin ---
  // C/D layout: col = lane&31, row_local = (e&3) + 8*(e>>2) + 4*half.
  unsigned* rbase = rowm + (size_t)(d * NB + b) * PTS + t0 * 32;
#pragma unroll
  for (int e = 0; e < 16; ++e) {
    float v = rm0[e];
    v = fminf(v, __shfl_xor(v, 1));
    v = fminf(v, __shfl_xor(v, 2));
    v = fminf(v, __shfl_xor(v, 4));
    v = fminf(v, __shfl_xor(v, 8));
    v = fminf(v, __shfl_xor(v, 16));
    if (l31 == e) {
      const int rl = (e & 3) + 8 * (e >> 2) + 4 * half;
      atomicMin(rbase + rl, __float_as_uint(fmaxf(v, 0.f)));
    }
  }
#pragma unroll
  for (int e = 0; e < 16; ++e) {
    float v = rm1[e];
    v = fminf(v, __shfl_xor(v, 1));
    v = fminf(v, __shfl_xor(v, 2));
    v = fminf(v, __shfl_xor(v, 4));
    v = fminf(v, __shfl_xor(v, 8));
    v = fminf(v, __shfl_xor(v, 16));
    if (l31 == e) {
      const int rl = 32 + (e & 3) + 8 * (e >> 2) + 4 * half;
      atomicMin(rbase + rl, __float_as_uint(fmaxf(v, 0.f)));
    }
  }
}

// ---- reduce: out[b] += partial sums of rowmin; 64 blocks (b, quarter) ----
__global__ __launch_bounds__(256) void reduce_rows(
    const unsigned* __restrict__ rowm, float* __restrict__ out) {
  const int b = blockIdx.x >> 2;
  const int seg = blockIdx.x & 3;
  const int tid = threadIdx.x;
  const unsigned* r0 = rowm + (size_t)b * PTS + seg * 1024;
  const unsigned* r1 = rowm + (size_t)(NB + b) * PTS + seg * 1024;
  float s = 0.f;
  for (int i = tid; i < 1024; i += 256)
    s += __uint_as_float(r0[i]) + __uint_as_float(r1[i]);
  s += __shfl_xor(s, 1);
  s += __shfl_xor(s, 2);
  s += __shfl_xor(s, 4);
  s += __shfl_xor(s, 8);
  s += __shfl_xor(s, 16);
  s += __shfl_xor(s, 32);
  __shared__ float acc[4];
  if ((tid & 63) == 0) acc[tid >> 6] = s;
  __syncthreads();
  if (tid == 0)
    atomicAdd(&out[b], (acc[0] + acc[1] + acc[2] + acc[3]) * (1.f / PTS));
}

extern "C" void kernel_launch(void* const* d_in, const int* in_sizes, int n_in,
                              void* d_out, int out_size, void* d_ws,
                              size_t ws_size, hipStream_t stream) {
  const float* x1 = (const float*)d_in[0];
  const float* x2 = (const float*)d_in[1];
  float* out = (float*)d_out;

  uint4* Bfr = (uint4*)d_ws;  // 2*NB*TILES*2*32 uint4 = 4 MB
  unsigned* rowm =
      (unsigned*)((char*)d_ws + (size_t)2 * NB * TILES * 2 * 32 * 16);

  prepack_b<<<(2 * NB * PTS) / 256, 256, 0, stream>>>(x1, x2, Bfr, rowm, out);
  dim3 grid(128, NB);  // x = (dir,b,cq) slice -> XCD = x%8 ; y = row-group
  chamfer_main<<<grid, 256, 0, stream>>>(x1, x2, Bfr, rowm);
  reduce_rows<<<64, 256, 0, stream>>>(rowm, out);
}

// Round 10
// 84.093 us; speedup vs baseline: 2.7589x; 1.1256x over previous
//
#include <hip/hip_runtime.h>

// Chamfer distance, B=16, N=M=4096, D=3.
// dist(i,j) = n1 + n2 - 2*x1.x2 as ONE bf16 MFMA per 32x32 tile (norms folded
// into padded K slots, hi/lo bf16 split => exact-grade; absmax 0.0 since R1).
// R14: single-generation grid + fused prepack.
//  - Floor recalc: 32x32x16 MFMA = 32 cyc/SIMD (2.5PF/256CU); total work
//    16384 cyc/SIMD = 6.8 us floor. R10-R13 ran at 14-38% MfmaUtil; limiter
//    is per-block overhead + cold-read latency, not HW peak.
//  - 512-thread blocks (8 waves x 2 row-tiles), grid 64x8 = 512 blocks =
//    exactly 2/CU (LDS 64KB x2 = 128 <= 160KB) -> one resident generation,
//    half R10's block count, quarter R12's.
//  - B-panel built IN LDS from raw points (4 pts/thread, prepack formulas
//    verbatim) -> prepack kernel + 4MB Bfr round-trip + cross-XCD cold reads
//    all eliminated. rowm init via hipMemsetAsync 0x7F (3.39e38 > any dist).
//  - Inner loop = R13 LDS ring verbatim (64 tiles, 32 g-iters).

typedef __attribute__((ext_vector_type(8))) __bf16 bf16x8;
typedef __attribute__((ext_vector_type(16))) float f32x16;

#define PTS 4096
#define NB 16

__device__ __forceinline__ unsigned f2bf(float f) {
  unsigned u = __float_as_uint(f);
  return (u + 0x7FFFu + ((u >> 16) & 1u)) >> 16;  // RNE bf16 bits
}
__device__ __forceinline__ float bf2f(unsigned s) {
  return __uint_as_float(s << 16);
}
__device__ __forceinline__ unsigned pk(unsigned lo, unsigned hi) {
  return (lo & 0xFFFFu) | (hi << 16);
}

// ---- main: 512 threads (8 waves). Block builds its 64-tile (2048-col)
// B-panel in LDS from raw points, then all 8 waves stream it (2 row-tiles
// per wave = 512 rows/block). grid.x = 64 slices (dir,b,ch) -> XCD = x%8 ;
// grid.y = 8 row-groups. One resident generation (512 blocks = 2/CU).
__global__ __launch_bounds__(512, 2) void chamfer_main(
    const float* __restrict__ x1, const float* __restrict__ x2,
    unsigned* __restrict__ rowm) {
  const int s  = blockIdx.x;           // 64 slices: (dir, batch, colhalf)
  const int d  = s & 1;
  const int b  = (s >> 1) & (NB - 1);
  const int ch = (s >> 5) & 1;
  const int rg = blockIdx.y;           // 8 row-groups of 512 rows

  const int tid  = threadIdx.x;
  const int lane = tid & 63;
  const int half = lane >> 5;          // K-half this lane supplies to MFMA
  const int l31  = lane & 31;
  const int wave = tid >> 6;           // 0..7

  __shared__ uint4 lds[4096];          // 64 tiles x 1 KB = 64 KB

  // --- build B-panel in LDS from raw col-side points (prepack formulas) ---
  // B k-vec: w0=[Hx Hy Hz Lx Ly Lz Hx Hy] w1=[Hz nh nl 1 1 0 0 0], H,L = -2q.
  const float* Q = d ? x1 : x2;        // col side = opposite of row side
  const int cbase = b * PTS + ch * 2048;
#pragma unroll
  for (int k = 0; k < 4; ++k) {
    const int j = tid + k * 512;       // 2048 panel points
    const float* q = Q + (size_t)(cbase + j) * 3;
    const float x = q[0], y = q[1], z = q[2];
    const float sx = -2.f * x, sy = -2.f * y, sz = -2.f * z;
    const unsigned Hx = f2bf(sx), Hy = f2bf(sy), Hz = f2bf(sz);
    const unsigned Lx = f2bf(sx - bf2f(Hx));
    const unsigned Ly = f2bf(sy - bf2f(Hy));
    const unsigned Lz = f2bf(sz - bf2f(Hz));
    const float n = fmaf(x, x, fmaf(y, y, z * z));
    const unsigned nh = f2bf(n), nl = f2bf(n - bf2f(nh));
    const unsigned one = 0x3F80u;
    uint4 w0, w1;
    w0.x = pk(Hx, Hy); w0.y = pk(Hz, Lx); w0.z = pk(Ly, Lz); w0.w = pk(Hx, Hy);
    w1.x = pk(Hz, nh); w1.y = pk(nl, one); w1.z = pk(one, 0u); w1.w = 0u;
    lds[(j >> 5) * 64 + (j & 31)]      = w0;  // half 0 (k 0..7)
    lds[(j >> 5) * 64 + 32 + (j & 31)] = w1;  // half 1 (k 8..15)
  }

  // --- build A fragments from raw points (row tiles t0, t0+1) ---
  // A k-vec: w0=[hx hy hz hx hy hz lx ly]  w1=[lz 1 1 nh nl 0 0 0]
  const float* P = d ? x2 : x1;
  const int t0 = rg * 16 + wave * 2;
  bf16x8 af[2];
#pragma unroll
  for (int rr = 0; rr < 2; ++rr) {
    const int r = (t0 + rr) * 32 + l31;
    const float* p = P + (size_t)(b * PTS + r) * 3;
    const float x = p[0], y = p[1], zc = p[2];
    const unsigned hx = f2bf(x), hy = f2bf(y), hz = f2bf(zc);
    const unsigned lx = f2bf(x - bf2f(hx));
    const unsigned ly = f2bf(y - bf2f(hy));
    const unsigned lz = f2bf(zc - bf2f(hz));
    const float n = fmaf(x, x, fmaf(y, y, zc * zc));
    const unsigned nh = f2bf(n), nl = f2bf(n - bf2f(nh));
    const unsigned one = 0x3F80u;
    uint4 w0, w1;
    w0.x = pk(hx, hy); w0.y = pk(hz, hx); w0.z = pk(hy, hz); w0.w = pk(lx, ly);
    w1.x = pk(lz, one); w1.y = pk(one, nh); w1.z = pk(nl, 0u); w1.w = 0u;
    uint4 w;
    w.x = half ? w1.x : w0.x; w.y = half ? w1.y : w0.y;
    w.z = half ? w1.z : w0.z; w.w = half ? w1.w : w0.w;
    af[rr] = *(const bf16x8*)&w;
  }
  const bf16x8 af0 = af[0], af1 = af[1];

  f32x16 zero;
#pragma unroll
  for (int e = 0; e < 16; ++e) zero[e] = 0.f;

  float rm0[16], rm1[16];
#pragma unroll
  for (int e = 0; e < 16; ++e) { rm0[e] = 3.0e38f; rm1[e] = 3.0e38f; }

  __syncthreads();  // panel staged (read-only afterwards: no more barriers)

  // --- stream 64 tiles from LDS; 4-slot ring, 2 reads in flight ---
  const uint4* tp = &lds[half * 32 + l31];  // tile stride = 64 uint4
  bf16x8 buf[4];
  buf[0] = *(const bf16x8*)&tp[0];
  buf[1] = *(const bf16x8*)&tp[64];

#pragma unroll 2
  for (int g = 0; g < 32; ++g) {
    const int cur = (g & 1) * 2;
    const int nxt = ((g + 1) & 1) * 2;
    const int pf  = ((g + 1) & 31) * 2;  // wrap: last prefetch redundant, safe
    buf[nxt]     = *(const bf16x8*)&tp[pf * 64];
    buf[nxt + 1] = *(const bf16x8*)&tp[(pf + 1) * 64];
    const bf16x8 b0 = buf[cur], b1 = buf[cur + 1];
    const f32x16 a00 =
        __builtin_amdgcn_mfma_f32_32x32x16_bf16(af0, b0, zero, 0, 0, 0);
    const f32x16 a01 =
        __builtin_amdgcn_mfma_f32_32x32x16_bf16(af0, b1, zero, 0, 0, 0);
#pragma unroll
    for (int e = 0; e < 16; ++e)
      rm0[e] = fminf(fminf(a00[e], a01[e]), rm0[e]);  // v_min3_f32
    const f32x16 a10 =
        __builtin_amdgcn_mfma_f32_32x32x16_bf16(af1, b0, zero, 0, 0, 0);
    const f32x16 a11 =
        __builtin_amdgcn_mfma_f32_32x32x16_bf16(af1, b1, zero, 0, 0, 0);
#pragma unroll
    for (int e = 0; e < 16; ++e)
      rm1[e] = fminf(fminf(a10[e], a11[e]), rm1[e]);
  }

  // --- per-row min over this wave's 32 cols-per-half, then uint atomicMin ---
  // C/D layout: col = lane&31, row_local = (e&3) + 8*(e>>2) + 4*half.
  unsigned* rbase = rowm + (size_t)(d * NB + b) * PTS + t0 * 32;
#pragma unroll
  for (int e = 0; e < 16; ++e) {
    float v = rm0[e];
    v = fminf(v, __shfl_xor(v, 1));
    v = fminf(v, __shfl_xor(v, 2));
    v = fminf(v, __shfl_xor(v, 4));
    v = fminf(v, __shfl_xor(v, 8));
    v = fminf(v, __shfl_xor(v, 16));
    if (l31 == e) {
      const int rl = (e & 3) + 8 * (e >> 2) + 4 * half;
      atomicMin(rbase + rl, __float_as_uint(fmaxf(v, 0.f)));
    }
  }
#pragma unroll
  for (int e = 0; e < 16; ++e) {
    float v = rm1[e];
    v = fminf(v, __shfl_xor(v, 1));
    v = fminf(v, __shfl_xor(v, 2));
    v = fminf(v, __shfl_xor(v, 4));
    v = fminf(v, __shfl_xor(v, 8));
    v = fminf(v, __shfl_xor(v, 16));
    if (l31 == e) {
      const int rl = 32 + (e & 3) + 8 * (e >> 2) + 4 * half;
      atomicMin(rbase + rl, __float_as_uint(fmaxf(v, 0.f)));
    }
  }
}

// ---- reduce: out[b] += partial sums of rowmin; 64 blocks (b, quarter) ----
__global__ __launch_bounds__(256) void reduce_rows(
    const unsigned* __restrict__ rowm, float* __restrict__ out) {
  const int b = blockIdx.x >> 2;
  const int seg = blockIdx.x & 3;
  const int tid = threadIdx.x;
  const unsigned* r0 = rowm + (size_t)b * PTS + seg * 1024;
  const unsigned* r1 = rowm + (size_t)(NB + b) * PTS + seg * 1024;
  float s = 0.f;
  for (int i = tid; i < 1024; i += 256)
    s += __uint_as_float(r0[i]) + __uint_as_float(r1[i]);
  s += __shfl_xor(s, 1);
  s += __shfl_xor(s, 2);
  s += __shfl_xor(s, 4);
  s += __shfl_xor(s, 8);
  s += __shfl_xor(s, 16);
  s += __shfl_xor(s, 32);
  __shared__ float acc[4];
  if ((tid & 63) == 0) acc[tid >> 6] = s;
  __syncthreads();
  if (tid == 0)
    atomicAdd(&out[b], (acc[0] + acc[1] + acc[2] + acc[3]) * (1.f / PTS));
}

extern "C" void kernel_launch(void* const* d_in, const int* in_sizes, int n_in,
                              void* d_out, int out_size, void* d_ws,
                              size_t ws_size, hipStream_t stream) {
  const float* x1 = (const float*)d_in[0];
  const float* x2 = (const float*)d_in[1];
  float* out = (float*)d_out;

  unsigned* rowm = (unsigned*)d_ws;  // 2*NB*PTS uint = 512 KB

  // 0x7F7F7F7F as float = 3.39e38 > any squared distance here: valid
  // atomicMin identity (positive-float bit order is monotone).
  hipMemsetAsync(rowm, 0x7F, (size_t)2 * NB * PTS * 4, stream);
  hipMemsetAsync(out, 0, NB * sizeof(float), stream);

  dim3 grid(64, 8);  // x = (dir,b,ch) slice -> XCD = x%8 ; y = row-group
  chamfer_main<<<grid, 512, 0, stream>>>(x1, x2, rowm);
  reduce_rows<<<64, 256, 0, stream>>>(rowm, out);
}